// Round 5
// baseline (518.991 us; speedup 1.0000x reference)
//
#include <hip/hip_runtime.h>
#include <hip/hip_bf16.h>
#include <math.h>

#define CIN   512
#define COUT  512
#define NB    16
#define WD    512
#define HIN   32
#define HUP   66
#define RES   64
#define LRELU 0.2f
#define ACT_GAIN 1.4142135623730951f

typedef __attribute__((ext_vector_type(8))) short short8;
typedef __attribute__((ext_vector_type(4))) float float4v;
typedef __attribute__((ext_vector_type(16))) float float16v;

// ---------------- styles = w @ A^T / sqrt(512) + bias ----------------
__global__ void styles2_kernel(const float* __restrict__ w,
                               const float* __restrict__ aw,
                               const float* __restrict__ ab,
                               float* __restrict__ styles) {
    int b = blockIdx.x;          // 16
    int cig = blockIdx.y;        // 8
    int lane = threadIdx.x & 63, wv = threadIdx.x >> 6;
    __shared__ float wsh[WD];
    for (int e = threadIdx.x; e < WD; e += 256) wsh[e] = w[b * WD + e];
    __syncthreads();
    for (int r = 0; r < 16; ++r) {
        int ci = cig * 64 + wv * 16 + r;
        const float* arow = aw + (size_t)ci * WD;
        float acc = 0.f;
        for (int k = lane; k < WD; k += 64) acc += arow[k] * wsh[k];
        for (int off = 32; off; off >>= 1) acc += __shfl_down(acc, off, 64);
        if (lane == 0)
            styles[b * CIN + ci] = acc * 0.04419417382415922f + ab[ci];
    }
}

// ---- weights: wsq fp32 + pre-flipped bf16 pack wb[cc][t][ci_hi][cout][ci_lo] ----
__global__ void prep_weights(const float* __restrict__ weight,
                             float* __restrict__ wsq,
                             __hip_bfloat16* __restrict__ wb) {
    int idx = blockIdx.x * 256 + threadIdx.x;   // 262144
    int co = idx & (COUT - 1);
    int ci = idx >> 9;
    const float* wp = weight + ((size_t)co * CIN + ci) * 9;
    int cc = ci >> 5, chi = (ci >> 3) & 3, clo = ci & 7;
    float s = 0.f;
#pragma unroll
    for (int t = 0; t < 9; ++t) {
        float v = wp[t];
        s += v * v;
        int tf = 8 - t;   // flipped tap
        wb[((((size_t)cc * 9 + tf) * 4 + chi) * COUT + co) * 8 + clo] = __float2bfloat16(v);
    }
    wsq[(size_t)co * CIN + ci] = s;
}

// ---------------- dcoef[b,co] = rsqrt( sum_ci wsq[co,ci]*styles^2 + 1e-8 ) ----------------
__global__ void dcoef2_kernel(const float* __restrict__ styles,
                              const float* __restrict__ wsq,
                              float* __restrict__ dcoef) {
    int b = blockIdx.x;          // 16
    int cog = blockIdx.y;        // 8
    int lane = threadIdx.x & 63, wv = threadIdx.x >> 6;
    __shared__ float s2[CIN];
    for (int e = threadIdx.x; e < CIN; e += 256) {
        float s = styles[b * CIN + e];
        s2[e] = s * s;
    }
    __syncthreads();
    for (int r = 0; r < 16; ++r) {
        int co = cog * 64 + wv * 16 + r;
        const float* qrow = wsq + (size_t)co * CIN;
        float acc = 0.f;
        for (int k = lane; k < CIN; k += 64) acc += qrow[k] * s2[k];
        for (int off = 32; off; off >>= 1) acc += __shfl_down(acc, off, 64);
        if (lane == 0) dcoef[b * COUT + co] = rsqrtf(acc + 1e-8f);
    }
}

// ------- fused upsample x2 (upfirdn [1,3,3,1]/8) * styles -> channels-last bf16 -------
// xs2[b][row(66)][col(66)][ci(512)]
// Coalesced: compute into LDS row-buffer ob (row stride 272B = 17x16B: holds the
// 256B payload, odd stride spreads banks), then write 256B-contiguous segments.
__global__ void upmod2_kernel(const float* __restrict__ x,
                              const float* __restrict__ styles,
                              __hip_bfloat16* __restrict__ xs2) {
    __shared__ float xt[128 * 68];
    __shared__ float ssh[128];
    __shared__ __align__(16) char ob[66 * 272];
    const int oh = blockIdx.x;        // 0..65
    const int ci0 = blockIdx.y * 128; // 4 groups
    const int b = blockIdx.z;
    int m0, m1; float a0, a1;
    if (oh & 1) { m0 = (oh - 3) >> 1; a0 = 0.125f; m1 = (oh - 1) >> 1; a1 = 0.375f; }
    else        { m0 = (oh >> 1) - 1; a0 = 0.375f; m1 = (oh >> 1);     a1 = 0.125f; }
    if (threadIdx.x < 128) ssh[threadIdx.x] = styles[b * CIN + ci0 + threadIdx.x] * 4.0f;
    for (int e = threadIdx.x; e < 2048; e += 256) {
        int ci = e >> 4, sel = (e >> 3) & 1, iw4 = e & 7;
        int m = sel ? m1 : m0;
        float4v v = (float4v)0.f;
        if (m >= 0 && m < HIN)
            v = *(const float4v*)(x + ((size_t)(b * CIN + ci0 + ci) * HIN + m) * HIN + iw4 * 4);
        *(float4v*)(&xt[ci * 68 + sel * 32 + iw4 * 4]) = v;
    }
    __syncthreads();
    for (int e = threadIdx.x; e < 1056; e += 256) {   // 16 cig * 66 ow
        int cig = e / 66;
        int ow = e - cig * 66;
        int n0i, n1i; float b0, b1;
        if (ow & 1) { n0i = (ow - 3) >> 1; b0 = 0.125f; n1i = (ow - 1) >> 1; b1 = 0.375f; }
        else        { n0i = (ow >> 1) - 1; b0 = 0.375f; n1i = (ow >> 1);     b1 = 0.125f; }
        bool c0 = (n0i >= 0) & (n0i < HIN);
        bool c1 = (n1i >= 0) & (n1i < HIN);
        short8 sv;
#pragma unroll
        for (int u = 0; u < 8; ++u) {
            int ci = cig * 8 + u;
            const float* base = &xt[ci * 68];
            float r0 = (c0 ? base[n0i] : 0.f) * b0 + (c1 ? base[n1i] : 0.f) * b1;
            float r1 = (c0 ? base[32 + n0i] : 0.f) * b0 + (c1 ? base[32 + n1i] : 0.f) * b1;
            float val = (a0 * r0 + a1 * r1) * ssh[ci];
            __hip_bfloat16 h = __float2bfloat16(val);
            sv[u] = *reinterpret_cast<const short*>(&h);
        }
        *reinterpret_cast<short8*>(ob + ow * 272 + cig * 16) = sv;
    }
    __syncthreads();
    for (int e = threadIdx.x; e < 1056; e += 256) {   // 66 ow * 16 chunks
        int ow = e >> 4, t16 = e & 15;
        short8 v = *reinterpret_cast<const short8*>(ob + ow * 272 + t16 * 16);
        *reinterpret_cast<short8*>(
            xs2 + (((size_t)b * HUP + oh) * HUP + ow) * CIN + ci0 + t16 * 8) = v;
    }
}

// ---------------- implicit-GEMM conv via MFMA bf16 32x32x16 ----------------
// 8 waves (512 thr); block tile M=512 px (8 rows, 1 row/wave), N=64 cout.
// Wave tile 64px x 64cout as 2x2 frags of 32x32 (acc 64 VGPR).
// A/B k-placement is consistent across both operands -> correct for any HW
// k-permutation; C/D per m74/m101: col=lane&31, row=(reg&3)+8*(reg>>2)+4*(lane>>5).
// Double-buffered LDS, same T3/T4 schedule and layouts as R3.
#define ABUF 43008
#define BBUF 36864
#define BUFSZ (ABUF + BBUF)          // 79872
#define LDS_TOT (2 * BUFSZ)          // 159744 <= 163840

__global__ __launch_bounds__(512, 1) void conv_mfma(
        const __hip_bfloat16* __restrict__ xs2,
        const __hip_bfloat16* __restrict__ wb,
        const float* __restrict__ dcoef,
        const float* __restrict__ bias,
        const float* __restrict__ noise,
        const float* __restrict__ nstr,
        float* __restrict__ out)
{
    extern __shared__ __align__(16) char smem[];
    const int tid = threadIdx.x;
    const int lane = tid & 63;
    const int wid = tid >> 6;        // 0..7
    const int li32 = lane & 31;
    const int hi = lane >> 5;        // 0..1
    const int mb = blockIdx.x;       // 0..7 -> rows y0..y0+7
    const int n0 = blockIdx.y * 64;  // cout base
    const int b  = blockIdx.z;
    const int y0 = mb * 8;

    // ---- staging descriptors ----
    int a_goff[6];
#pragma unroll
    for (int k = 0; k < 6; ++k) {
        int n = wid + k * 8;
        int s = n * 64 + lane;          // 16B slot id, valid 0..2639
        if (s > 2639) s = 2639;         // clamp tail into pad region
        int r = s / 264;
        int rem = s - r * 264;
        int chi = rem / 66;
        int col = rem - chi * 66;
        a_goff[k] = ((b * HUP + y0 + r) * HUP + col) * CIN + chi * 8;
    }
    int b_goff[5];
#pragma unroll
    for (int k = 0; k < 5; ++k) {
        int sl = wid + k * 8;           // t = sl>>2, chi = sl&3
        b_goff[k] = (sl * COUT + n0 + lane) * 8;
    }

    float16v acc[2][2];
#pragma unroll
    for (int i = 0; i < 2; ++i)
#pragma unroll
        for (int j = 0; j < 2; ++j) acc[i][j] = (float16v)0.f;

    const char* xg = (const char*)xs2;
    const char* wg = (const char*)wb;

#define STAGE(CC, BUFB) do {                                                  \
        _Pragma("unroll")                                                     \
        for (int k = 0; k < 5; ++k) {                                         \
            int sl = wid + k * 8;                                             \
            if (sl < 36) {                                                    \
                long ge = (long)(b_goff[k] + (CC) * 147456);                  \
                __builtin_amdgcn_global_load_lds(                             \
                    (const __attribute__((address_space(1))) char*)(wg + ge * 2), \
                    (__attribute__((address_space(3))) char*)(smem + (BUFB) + ABUF + sl * 1024), \
                    16, 0, 0);                                                \
            }                                                                 \
        }                                                                     \
        _Pragma("unroll")                                                     \
        for (int k = 0; k < 6; ++k) {                                         \
            int n = wid + k * 8;                                              \
            if (n < 42) {                                                     \
                long ge = (long)(a_goff[k] + (CC) * 32);                      \
                __builtin_amdgcn_global_load_lds(                             \
                    (const __attribute__((address_space(1))) char*)(xg + ge * 2), \
                    (__attribute__((address_space(3))) char*)(smem + (BUFB) + n * 1024), \
                    16, 0, 0);                                                \
            }                                                                 \
        }                                                                     \
    } while (0)

#define COMPUTE(BUFB) do {                                                    \
        __builtin_amdgcn_s_setprio(1);                                        \
        _Pragma("unroll")                                                     \
        for (int t = 0; t < 9; ++t) {                                         \
            const int kh = t / 3, kw = t - kh * 3;                            \
            _Pragma("unroll")                                                 \
            for (int ks = 0; ks < 2; ++ks) {                                  \
                short8 bfr[2];                                                \
                _Pragma("unroll")                                             \
                for (int nf = 0; nf < 2; ++nf)                                \
                    bfr[nf] = *(const short8*)(smem + (BUFB) + ABUF +         \
                            (((t * 4 + ks * 2 + hi) * 64) + nf * 32 + li32) * 16); \
                _Pragma("unroll")                                             \
                for (int mf = 0; mf < 2; ++mf) {                              \
                    short8 af = *(const short8*)(smem + (BUFB) +              \
                            ((((wid + kh) * 4 + ks * 2 + hi) * 66) +          \
                             (mf * 32 + li32 + kw)) * 16);                    \
                    _Pragma("unroll")                                         \
                    for (int nf = 0; nf < 2; ++nf)                            \
                        acc[mf][nf] = __builtin_amdgcn_mfma_f32_32x32x16_bf16(\
                            af, bfr[nf], acc[mf][nf], 0, 0, 0);               \
                }                                                             \
            }                                                                 \
        }                                                                     \
        __builtin_amdgcn_s_setprio(0);                                        \
    } while (0)

#define SYNC() do {                                                           \
        asm volatile("s_waitcnt vmcnt(0)" ::: "memory");                      \
        __builtin_amdgcn_s_barrier();                                         \
    } while (0)

    // prologue: stage cc=0 into buf0
    STAGE(0, 0);
    SYNC();

#pragma unroll 1
    for (int cc = 0; cc < 16; cc += 2) {
        STAGE(cc + 1, BUFSZ);        // issue early: latency hides under taps
        COMPUTE(0);
        SYNC();                      // drain (cheap) + one barrier
        if (cc + 2 < 16) STAGE(cc + 2, 0);
        COMPUTE(BUFSZ);
        SYNC();
    }

#undef STAGE
#undef COMPUTE
#undef SYNC

    // ---- epilogue: *dcoef + noise + bias -> lrelu*gain ----
    const float ns = nstr[0];
    const int row = y0 + wid;
#pragma unroll
    for (int nf = 0; nf < 2; ++nf) {
        int cout = n0 + nf * 32 + li32;
        float dc = dcoef[b * COUT + cout];
        float bs = bias[cout];
        float* op = out + ((size_t)(b * COUT + cout) * RES + row) * RES;
#pragma unroll
        for (int mf = 0; mf < 2; ++mf) {
#pragma unroll
            for (int r2 = 0; r2 < 4; ++r2) {
                int x0 = mf * 32 + hi * 4 + r2 * 8;
                float4v nz = *(const float4v*)(noise + row * RES + x0);
                float4v r;
                r.x = acc[mf][nf][r2 * 4 + 0] * dc + nz.x * ns + bs;
                r.y = acc[mf][nf][r2 * 4 + 1] * dc + nz.y * ns + bs;
                r.z = acc[mf][nf][r2 * 4 + 2] * dc + nz.z * ns + bs;
                r.w = acc[mf][nf][r2 * 4 + 3] * dc + nz.w * ns + bs;
                r.x = (r.x > 0.f ? r.x : LRELU * r.x) * ACT_GAIN;
                r.y = (r.y > 0.f ? r.y : LRELU * r.y) * ACT_GAIN;
                r.z = (r.z > 0.f ? r.z : LRELU * r.z) * ACT_GAIN;
                r.w = (r.w > 0.f ? r.w : LRELU * r.w) * ACT_GAIN;
                *(float4v*)(op + x0) = r;
            }
        }
    }
}

extern "C" void kernel_launch(void* const* d_in, const int* in_sizes, int n_in,
                              void* d_out, int out_size, void* d_ws, size_t ws_size,
                              hipStream_t stream) {
    (void)in_sizes; (void)n_in; (void)out_size; (void)ws_size;
    const float* x     = (const float*)d_in[0];
    const float* w     = (const float*)d_in[1];
    const float* aw    = (const float*)d_in[2];
    const float* ab    = (const float*)d_in[3];
    const float* wt    = (const float*)d_in[4];
    const float* bias  = (const float*)d_in[5];
    const float* noise = (const float*)d_in[6];
    const float* nstr  = (const float*)d_in[7];
    float* out = (float*)d_out;

    static bool init = false;
    if (!init) {
        hipFuncSetAttribute(reinterpret_cast<const void*>(conv_mfma),
                            hipFuncAttributeMaxDynamicSharedMemorySize, LDS_TOT);
        init = true;
    }

    char* ws = (char*)d_ws;
    float* styles = (float*)ws;                                   // 32 KB
    float* dcoef  = (float*)(ws + 32768);                         // 32 KB
    float* wsq    = (float*)(ws + 65536);                         // 1 MB
    __hip_bfloat16* wb  = (__hip_bfloat16*)(ws + 65536 + 1048576);          // 4.72 MB
    __hip_bfloat16* xs2 = (__hip_bfloat16*)(ws + 65536 + 1048576 + 4718592); // 71.4 MB

    styles2_kernel<<<dim3(NB, 8), dim3(256), 0, stream>>>(w, aw, ab, styles);
    prep_weights<<<dim3(1024), dim3(256), 0, stream>>>(wt, wsq, wb);
    dcoef2_kernel<<<dim3(NB, 8), dim3(256), 0, stream>>>(styles, wsq, dcoef);
    upmod2_kernel<<<dim3(HUP, 4, NB), dim3(256), 0, stream>>>(x, styles, xs2);
    conv_mfma<<<dim3(8, 8, NB), dim3(512), LDS_TOT, stream>>>(
        xs2, wb, dcoef, bias, noise, nstr, out);
}

// Round 6
// 509.441 us; speedup vs baseline: 1.0187x; 1.0187x over previous
//
#include <hip/hip_runtime.h>
#include <hip/hip_bf16.h>
#include <math.h>

#define CIN   512
#define COUT  512
#define NB    16
#define WD    512
#define HIN   32
#define HUP   66
#define RES   64
#define LRELU 0.2f
#define ACT_GAIN 1.4142135623730951f

typedef __attribute__((ext_vector_type(8))) short short8;
typedef __attribute__((ext_vector_type(4))) float float4v;
typedef __attribute__((ext_vector_type(16))) float float16v;

// ---------------- styles = w @ A^T / sqrt(512) + bias ----------------
__global__ void styles2_kernel(const float* __restrict__ w,
                               const float* __restrict__ aw,
                               const float* __restrict__ ab,
                               float* __restrict__ styles) {
    int b = blockIdx.x;          // 16
    int cig = blockIdx.y;        // 8
    int lane = threadIdx.x & 63, wv = threadIdx.x >> 6;
    __shared__ float wsh[WD];
    for (int e = threadIdx.x; e < WD; e += 256) wsh[e] = w[b * WD + e];
    __syncthreads();
    for (int r = 0; r < 16; ++r) {
        int ci = cig * 64 + wv * 16 + r;
        const float* arow = aw + (size_t)ci * WD;
        float acc = 0.f;
        for (int k = lane; k < WD; k += 64) acc += arow[k] * wsh[k];
        for (int off = 32; off; off >>= 1) acc += __shfl_down(acc, off, 64);
        if (lane == 0)
            styles[b * CIN + ci] = acc * 0.04419417382415922f + ab[ci];
    }
}

// ---- weights: wsq fp32 + pre-flipped bf16 pack wb[cc][t][ci_hi][cout][ci_lo] ----
__global__ void prep_weights(const float* __restrict__ weight,
                             float* __restrict__ wsq,
                             __hip_bfloat16* __restrict__ wb) {
    int idx = blockIdx.x * 256 + threadIdx.x;   // 262144
    int co = idx & (COUT - 1);
    int ci = idx >> 9;
    const float* wp = weight + ((size_t)co * CIN + ci) * 9;
    int cc = ci >> 5, chi = (ci >> 3) & 3, clo = ci & 7;
    float s = 0.f;
#pragma unroll
    for (int t = 0; t < 9; ++t) {
        float v = wp[t];
        s += v * v;
        int tf = 8 - t;   // flipped tap
        wb[((((size_t)cc * 9 + tf) * 4 + chi) * COUT + co) * 8 + clo] = __float2bfloat16(v);
    }
    wsq[(size_t)co * CIN + ci] = s;
}

// ---------------- dcoef[b,co] = rsqrt( sum_ci wsq[co,ci]*styles^2 + 1e-8 ) ----------------
__global__ void dcoef2_kernel(const float* __restrict__ styles,
                              const float* __restrict__ wsq,
                              float* __restrict__ dcoef) {
    int b = blockIdx.x;          // 16
    int cog = blockIdx.y;        // 8
    int lane = threadIdx.x & 63, wv = threadIdx.x >> 6;
    __shared__ float s2[CIN];
    for (int e = threadIdx.x; e < CIN; e += 256) {
        float s = styles[b * CIN + e];
        s2[e] = s * s;
    }
    __syncthreads();
    for (int r = 0; r < 16; ++r) {
        int co = cog * 64 + wv * 16 + r;
        const float* qrow = wsq + (size_t)co * CIN;
        float acc = 0.f;
        for (int k = lane; k < CIN; k += 64) acc += qrow[k] * s2[k];
        for (int off = 32; off; off >>= 1) acc += __shfl_down(acc, off, 64);
        if (lane == 0) dcoef[b * COUT + co] = rsqrtf(acc + 1e-8f);
    }
}

// ------- fused upsample x2 (upfirdn [1,3,3,1]/8) * styles -> channels-last bf16 -------
// xs2[b][row(66)][col(66)][ci(512)]
__global__ void upmod2_kernel(const float* __restrict__ x,
                              const float* __restrict__ styles,
                              __hip_bfloat16* __restrict__ xs2) {
    __shared__ float xt[128 * 68];
    __shared__ float ssh[128];
    __shared__ __align__(16) char ob[66 * 272];
    const int oh = blockIdx.x;        // 0..65
    const int ci0 = blockIdx.y * 128; // 4 groups
    const int b = blockIdx.z;
    int m0, m1; float a0, a1;
    if (oh & 1) { m0 = (oh - 3) >> 1; a0 = 0.125f; m1 = (oh - 1) >> 1; a1 = 0.375f; }
    else        { m0 = (oh >> 1) - 1; a0 = 0.375f; m1 = (oh >> 1);     a1 = 0.125f; }
    if (threadIdx.x < 128) ssh[threadIdx.x] = styles[b * CIN + ci0 + threadIdx.x] * 4.0f;
    for (int e = threadIdx.x; e < 2048; e += 256) {
        int ci = e >> 4, sel = (e >> 3) & 1, iw4 = e & 7;
        int m = sel ? m1 : m0;
        float4v v = (float4v)0.f;
        if (m >= 0 && m < HIN)
            v = *(const float4v*)(x + ((size_t)(b * CIN + ci0 + ci) * HIN + m) * HIN + iw4 * 4);
        *(float4v*)(&xt[ci * 68 + sel * 32 + iw4 * 4]) = v;
    }
    __syncthreads();
    for (int e = threadIdx.x; e < 1056; e += 256) {   // 16 cig * 66 ow
        int cig = e / 66;
        int ow = e - cig * 66;
        int n0i, n1i; float b0, b1;
        if (ow & 1) { n0i = (ow - 3) >> 1; b0 = 0.125f; n1i = (ow - 1) >> 1; b1 = 0.375f; }
        else        { n0i = (ow >> 1) - 1; b0 = 0.375f; n1i = (ow >> 1);     b1 = 0.125f; }
        bool c0 = (n0i >= 0) & (n0i < HIN);
        bool c1 = (n1i >= 0) & (n1i < HIN);
        short8 sv;
#pragma unroll
        for (int u = 0; u < 8; ++u) {
            int ci = cig * 8 + u;
            const float* base = &xt[ci * 68];
            float r0 = (c0 ? base[n0i] : 0.f) * b0 + (c1 ? base[n1i] : 0.f) * b1;
            float r1 = (c0 ? base[32 + n0i] : 0.f) * b0 + (c1 ? base[32 + n1i] : 0.f) * b1;
            float val = (a0 * r0 + a1 * r1) * ssh[ci];
            __hip_bfloat16 h = __float2bfloat16(val);
            sv[u] = *reinterpret_cast<const short*>(&h);
        }
        *reinterpret_cast<short8*>(ob + ow * 272 + cig * 16) = sv;
    }
    __syncthreads();
    for (int e = threadIdx.x; e < 1056; e += 256) {   // 66 ow * 16 chunks
        int ow = e >> 4, t16 = e & 15;
        short8 v = *reinterpret_cast<const short8*>(ob + ow * 272 + t16 * 16);
        *reinterpret_cast<short8*>(
            xs2 + (((size_t)b * HUP + oh) * HUP + ow) * CIN + ci0 + t16 * 8) = v;
    }
}

// ---------------- implicit-GEMM conv via MFMA bf16 32x32x16 ----------------
// 8 waves (512 thr); block tile M=512 px (8 rows, 1 row/wave), N=64 cout.
// Wave tile 64px x 64cout as 2x2 frags of 32x32 (acc 64 VGPR).
// SOFTWARE-PIPELINED inner loop (2-slot): issue step n+1's 4 ds_read_b128,
// then step n's 4 MFMAs; sched_group_barrier pins the [DS4][MFMA4] pattern
// so the LDS pipe processes step n+1 while the matrix pipes run step n.
// (R5 evidence: default scheduling fully serialized DS (6.9k cyc/cc/CU) and
// MFMA (4.6k) -> 11.1k measured. Target: max() not sum().)
#define ABUF 43008
#define BBUF 36864
#define BUFSZ (ABUF + BBUF)          // 79872
#define LDS_TOT (2 * BUFSZ)          // 159744 <= 163840

__global__ __launch_bounds__(512, 1) void conv_mfma(
        const __hip_bfloat16* __restrict__ xs2,
        const __hip_bfloat16* __restrict__ wb,
        const float* __restrict__ dcoef,
        const float* __restrict__ bias,
        const float* __restrict__ noise,
        const float* __restrict__ nstr,
        float* __restrict__ out)
{
    extern __shared__ __align__(16) char smem[];
    const int tid = threadIdx.x;
    const int lane = tid & 63;
    const int wid = tid >> 6;        // 0..7
    const int li32 = lane & 31;
    const int hi = lane >> 5;        // 0..1
    const int mb = blockIdx.x;       // 0..7 -> rows y0..y0+7
    const int n0 = blockIdx.y * 64;  // cout base
    const int b  = blockIdx.z;
    const int y0 = mb * 8;

    // ---- staging descriptors ----
    int a_goff[6];
#pragma unroll
    for (int k = 0; k < 6; ++k) {
        int n = wid + k * 8;
        int s = n * 64 + lane;          // 16B slot id, valid 0..2639
        if (s > 2639) s = 2639;         // clamp tail into pad region
        int r = s / 264;
        int rem = s - r * 264;
        int chi = rem / 66;
        int col = rem - chi * 66;
        a_goff[k] = ((b * HUP + y0 + r) * HUP + col) * CIN + chi * 8;
    }
    int b_goff[5];
#pragma unroll
    for (int k = 0; k < 5; ++k) {
        int sl = wid + k * 8;           // t = sl>>2, chi = sl&3
        b_goff[k] = (sl * COUT + n0 + lane) * 8;
    }

    float16v acc[2][2];
#pragma unroll
    for (int i = 0; i < 2; ++i)
#pragma unroll
        for (int j = 0; j < 2; ++j) acc[i][j] = (float16v)0.f;

    const char* xg = (const char*)xs2;
    const char* wg = (const char*)wb;

#define STAGE(CC, BUFB) do {                                                  \
        _Pragma("unroll")                                                     \
        for (int k = 0; k < 5; ++k) {                                         \
            int sl = wid + k * 8;                                             \
            if (sl < 36) {                                                    \
                long ge = (long)(b_goff[k] + (CC) * 147456);                  \
                __builtin_amdgcn_global_load_lds(                             \
                    (const __attribute__((address_space(1))) char*)(wg + ge * 2), \
                    (__attribute__((address_space(3))) char*)(smem + (BUFB) + ABUF + sl * 1024), \
                    16, 0, 0);                                                \
            }                                                                 \
        }                                                                     \
        _Pragma("unroll")                                                     \
        for (int k = 0; k < 6; ++k) {                                         \
            int n = wid + k * 8;                                              \
            if (n < 42) {                                                     \
                long ge = (long)(a_goff[k] + (CC) * 32);                      \
                __builtin_amdgcn_global_load_lds(                             \
                    (const __attribute__((address_space(1))) char*)(xg + ge * 2), \
                    (__attribute__((address_space(3))) char*)(smem + (BUFB) + n * 1024), \
                    16, 0, 0);                                                \
            }                                                                 \
        }                                                                     \
    } while (0)

// load the 4 fragments of step S (t = S/2, ks = S&1) into slot SLOT
#define LOADF(BUFB, S, SLOT) do {                                             \
        const int t_ = (S) >> 1, ks_ = (S) & 1;                               \
        const int kh_ = t_ / 3, kw_ = t_ - kh_ * 3;                           \
        _Pragma("unroll")                                                     \
        for (int nf = 0; nf < 2; ++nf)                                        \
            fB[SLOT][nf] = *(const short8*)(smem + (BUFB) + ABUF +            \
                    (((t_ * 4 + ks_ * 2 + hi) * 64) + nf * 32 + li32) * 16);  \
        _Pragma("unroll")                                                     \
        for (int mf = 0; mf < 2; ++mf)                                        \
            fA[SLOT][mf] = *(const short8*)(smem + (BUFB) +                   \
                    ((((wid + kh_) * 4 + ks_ * 2 + hi) * 66) +                \
                     (mf * 32 + li32 + kw_)) * 16);                           \
    } while (0)

#define COMPUTE(BUFB) do {                                                    \
        short8 fA[2][2], fB[2][2];                                            \
        LOADF(BUFB, 0, 0);                                                    \
        __builtin_amdgcn_sched_group_barrier(0x100, 4, 0); /* DS4: step0 */   \
        __builtin_amdgcn_s_setprio(1);                                        \
        _Pragma("unroll")                                                     \
        for (int s = 0; s < 18; ++s) {                                        \
            const int cur = s & 1, nxt = cur ^ 1;                             \
            if (s < 17) LOADF(BUFB, s + 1, nxt);                              \
            _Pragma("unroll")                                                 \
            for (int mf = 0; mf < 2; ++mf)                                    \
                _Pragma("unroll")                                             \
                for (int nf = 0; nf < 2; ++nf)                                \
                    acc[mf][nf] = __builtin_amdgcn_mfma_f32_32x32x16_bf16(    \
                        fA[cur][mf], fB[cur][nf], acc[mf][nf], 0, 0, 0);      \
            if (s < 17)                                                       \
                __builtin_amdgcn_sched_group_barrier(0x100, 4, 0); /* DS4 n+1 */ \
            __builtin_amdgcn_sched_group_barrier(0x008, 4, 0);     /* MFMA4 n */ \
        }                                                                     \
        __builtin_amdgcn_s_setprio(0);                                        \
    } while (0)

#define SYNC() do {                                                           \
        asm volatile("s_waitcnt vmcnt(0)" ::: "memory");                      \
        __builtin_amdgcn_s_barrier();                                         \
    } while (0)

    // prologue: stage cc=0 into buf0
    STAGE(0, 0);
    SYNC();

#pragma unroll 1
    for (int cc = 0; cc < 16; cc += 2) {
        STAGE(cc + 1, BUFSZ);        // issue early: latency hides under taps
        COMPUTE(0);
        SYNC();                      // drain (cheap) + one barrier
        if (cc + 2 < 16) STAGE(cc + 2, 0);
        COMPUTE(BUFSZ);
        SYNC();
    }

#undef STAGE
#undef LOADF
#undef COMPUTE
#undef SYNC

    // ---- epilogue: *dcoef + noise + bias -> lrelu*gain ----
    const float ns = nstr[0];
    const int row = y0 + wid;
#pragma unroll
    for (int nf = 0; nf < 2; ++nf) {
        int cout = n0 + nf * 32 + li32;
        float dc = dcoef[b * COUT + cout];
        float bs = bias[cout];
        float* op = out + ((size_t)(b * COUT + cout) * RES + row) * RES;
#pragma unroll
        for (int mf = 0; mf < 2; ++mf) {
#pragma unroll
            for (int r2 = 0; r2 < 4; ++r2) {
                int x0 = mf * 32 + hi * 4 + r2 * 8;
                float4v nz = *(const float4v*)(noise + row * RES + x0);
                float4v r;
                r.x = acc[mf][nf][r2 * 4 + 0] * dc + nz.x * ns + bs;
                r.y = acc[mf][nf][r2 * 4 + 1] * dc + nz.y * ns + bs;
                r.z = acc[mf][nf][r2 * 4 + 2] * dc + nz.z * ns + bs;
                r.w = acc[mf][nf][r2 * 4 + 3] * dc + nz.w * ns + bs;
                r.x = (r.x > 0.f ? r.x : LRELU * r.x) * ACT_GAIN;
                r.y = (r.y > 0.f ? r.y : LRELU * r.y) * ACT_GAIN;
                r.z = (r.z > 0.f ? r.z : LRELU * r.z) * ACT_GAIN;
                r.w = (r.w > 0.f ? r.w : LRELU * r.w) * ACT_GAIN;
                *(float4v*)(op + x0) = r;
            }
        }
    }
}

extern "C" void kernel_launch(void* const* d_in, const int* in_sizes, int n_in,
                              void* d_out, int out_size, void* d_ws, size_t ws_size,
                              hipStream_t stream) {
    (void)in_sizes; (void)n_in; (void)out_size; (void)ws_size;
    const float* x     = (const float*)d_in[0];
    const float* w     = (const float*)d_in[1];
    const float* aw    = (const float*)d_in[2];
    const float* ab    = (const float*)d_in[3];
    const float* wt    = (const float*)d_in[4];
    const float* bias  = (const float*)d_in[5];
    const float* noise = (const float*)d_in[6];
    const float* nstr  = (const float*)d_in[7];
    float* out = (float*)d_out;

    static bool init = false;
    if (!init) {
        hipFuncSetAttribute(reinterpret_cast<const void*>(conv_mfma),
                            hipFuncAttributeMaxDynamicSharedMemorySize, LDS_TOT);
        init = true;
    }

    char* ws = (char*)d_ws;
    float* styles = (float*)ws;                                   // 32 KB
    float* dcoef  = (float*)(ws + 32768);                         // 32 KB
    float* wsq    = (float*)(ws + 65536);                         // 1 MB
    __hip_bfloat16* wb  = (__hip_bfloat16*)(ws + 65536 + 1048576);          // 4.72 MB
    __hip_bfloat16* xs2 = (__hip_bfloat16*)(ws + 65536 + 1048576 + 4718592); // 71.4 MB

    styles2_kernel<<<dim3(NB, 8), dim3(256), 0, stream>>>(w, aw, ab, styles);
    prep_weights<<<dim3(1024), dim3(256), 0, stream>>>(wt, wsq, wb);
    dcoef2_kernel<<<dim3(NB, 8), dim3(256), 0, stream>>>(styles, wsq, dcoef);
    upmod2_kernel<<<dim3(HUP, 4, NB), dim3(256), 0, stream>>>(x, styles, xs2);
    conv_mfma<<<dim3(8, 8, NB), dim3(512), LDS_TOT, stream>>>(
        xs2, wb, dcoef, bias, noise, nstr, out);
}